// Round 2
// baseline (939.462 us; speedup 1.0000x reference)
//
#include <hip/hip_runtime.h>
#include <math.h>

// Fused Conv3d(3->16, k=3, valid) + bias + min over D + softmax over C.
// N=16, CIN=3, COUT=16, K=3, D=H=W=64 -> out [16,16,62,62] fp32.
//
// R2: depth-streaming direct conv, 2x4 pixels/thread (tile 8x16), chunked
// LDS staging of 8 d-slices per barrier pair. Each thread owns one output
// channel (81 weights in VGPRs). Ring of 3 accumulators handles kd as d
// streams; min over d' online; softmax via 16-lane shuffles (co = lane&15).

#define CH 8  // d-slices per staged chunk

__global__ __launch_bounds__(256, 2) void conv3d_min_softmax(
    const float* __restrict__ x,     // [16,3,64,64,64]
    const float* __restrict__ wgt,   // [16,3,3,3,3]
    const float* __restrict__ bias,  // [16]
    float* __restrict__ out)         // [16,16,62,62]
{
    const int tid = threadIdx.x;
    const int co  = tid & 15;          // output channel on lane bits 0..3
    const int s   = tid >> 4;          // 0..15 strip id
    const int hh  = (s >> 2) * 2;      // output rows hh, hh+1 (0,2,4,6)
    const int ww  = (s & 3) * 4;       // output cols ww..ww+3 (0,4,8,12)
    const int n   = blockIdx.z;
    const int h0  = blockIdx.y * 8;    // 8 h-tiles cover rows 0..63 (62 valid)
    const int w0  = blockIdx.x * 16;   // 4 w-tiles cover cols 0..63 (62 valid)

    // staged x: 3 ci x CH d x 10 rows x 20 cols (18 valid, row stride 20
    // keeps float4 alignment; stride-20 f4 writes tile all 32 banks)
    __shared__ __align__(16) float sx[3][CH][10][20];

    // per-thread weights: idx = ci*27 + kd*9 + kh*3 + kw
    float wreg[81];
#pragma unroll
    for (int i = 0; i < 81; ++i) wreg[i] = wgt[co * 81 + i];

    // ring: A0 completes this step (kd=2), A1 next (kd=1), A2 after (kd=0)
    float A0[2][4], A1[2][4], A2[2][4], mv[2][4];
#pragma unroll
    for (int o = 0; o < 2; ++o)
#pragma unroll
        for (int p = 0; p < 4; ++p) {
            A0[o][p] = A1[o][p] = A2[o][p] = 0.f;
            mv[o][p] = 1e30f;
        }

    const float* xn = x + (size_t)n * 3 * 64 * 64 * 64;

    for (int c = 0; c < 64 / CH; ++c) {
        const int d0 = c * CH;
        // ---- stage 3 x CH x 10 x 18(->20) slice: 1200 float4 ----
        __syncthreads();
        for (int F = tid; F < 3 * CH * 10 * 5; F += 256) {
            int rowid = F / 5;               // ci*(CH*10) + dd*10 + r
            int g     = F - rowid * 5;       // col group (4 floats)
            int ci    = rowid / (CH * 10);
            int rem   = rowid - ci * (CH * 10);
            int dd    = rem / 10;
            int r     = rem - dd * 10;
            int gh    = min(h0 + r, 63);     // clamp: edge halo, unused
            int gw    = min(w0 + g * 4, 60); // clamp: cols 62..67 unused
            const float4 v = *(const float4*)
                &xn[(((size_t)ci * 64 + d0 + dd) * 64 + gh) * 64 + gw];
            *(float4*)&sx[ci][dd][r][g * 4] = v;
        }
        __syncthreads();

        // ---- compute CH d-steps from LDS ----
#pragma unroll 2
        for (int dd = 0; dd < CH; ++dd) {
#pragma unroll
            for (int ci = 0; ci < 3; ++ci) {
                // cache 4 x-rows (hh..hh+3), 6 floats each, from col ww
                float xr[4][6];
#pragma unroll
                for (int rr = 0; rr < 4; ++rr) {
                    const float4 a = *(const float4*)&sx[ci][dd][hh + rr][ww];
                    const float2 b = *(const float2*)&sx[ci][dd][hh + rr][ww + 4];
                    xr[rr][0] = a.x; xr[rr][1] = a.y; xr[rr][2] = a.z;
                    xr[rr][3] = a.w; xr[rr][4] = b.x; xr[rr][5] = b.y;
                }
#pragma unroll
                for (int o = 0; o < 2; ++o) {
#pragma unroll
                    for (int kh = 0; kh < 3; ++kh) {
#pragma unroll
                        for (int kw = 0; kw < 3; ++kw) {
                            const float wk0 = wreg[ci * 27 +  0 + kh * 3 + kw];
                            const float wk1 = wreg[ci * 27 +  9 + kh * 3 + kw];
                            const float wk2 = wreg[ci * 27 + 18 + kh * 3 + kw];
#pragma unroll
                            for (int p = 0; p < 4; ++p) {
                                const float xv = xr[o + kh][kw + p];
                                A2[o][p] = fmaf(xv, wk0, A2[o][p]); // d' = d
                                A1[o][p] = fmaf(xv, wk1, A1[o][p]); // d' = d-1
                                A0[o][p] = fmaf(xv, wk2, A0[o][p]); // d' = d-2
                            }
                        }
                    }
                }
            }
            const int d = d0 + dd;
            if (d >= 2) {
#pragma unroll
                for (int o = 0; o < 2; ++o)
#pragma unroll
                    for (int p = 0; p < 4; ++p)
                        mv[o][p] = fminf(mv[o][p], A0[o][p]);
            }
#pragma unroll
            for (int o = 0; o < 2; ++o)
#pragma unroll
                for (int p = 0; p < 4; ++p) {
                    A0[o][p] = A1[o][p];
                    A1[o][p] = A2[o][p];
                    A2[o][p] = 0.f;
                }
        }
    }

    // ---- epilogue: bias, softmax over 16 channels (lanes), store ----
    const float bv = bias[co];
#pragma unroll
    for (int o = 0; o < 2; ++o) {
        const int hp = h0 + hh + o;
#pragma unroll
        for (int p = 0; p < 4; ++p) {
            float v = mv[o][p] + bv;
            float mx = v;
#pragma unroll
            for (int off = 1; off < 16; off <<= 1)
                mx = fmaxf(mx, __shfl_xor(mx, off, 64));
            float e = __expf(v - mx);
            float sum = e;
#pragma unroll
            for (int off = 1; off < 16; off <<= 1)
                sum += __shfl_xor(sum, off, 64);
            const int wp = w0 + ww + p;
            if (hp < 62 && wp < 62)
                out[(((size_t)n * 16 + co) * 62 + hp) * 62 + wp] = e / sum;
        }
    }
}

extern "C" void kernel_launch(void* const* d_in, const int* in_sizes, int n_in,
                              void* d_out, int out_size, void* d_ws, size_t ws_size,
                              hipStream_t stream) {
    const float* x    = (const float*)d_in[0];
    const float* wgt  = (const float*)d_in[1];
    const float* bias = (const float*)d_in[2];
    float* out        = (float*)d_out;
    dim3 grid(4, 8, 16);   // (w-tiles, h-tiles, n)
    dim3 block(256);
    hipLaunchKernelGGL(conv3d_min_softmax, grid, block, 0, stream,
                       x, wgt, bias, out);
}

// Round 3
// 305.789 us; speedup vs baseline: 3.0723x; 3.0723x over previous
//
#include <hip/hip_runtime.h>
#include <math.h>

// Fused Conv3d(3->16, k=3, valid) + bias + min over D + softmax over C.
// N=16, CIN=3, COUT=16, K=3, D=H=W=64 -> out [16,16,62,62] fp32.
//
// R3: R2 structure (2x4 pixels/thread, tile 8x16, CH=8 chunked LDS staging)
// WITHOUT the launch_bounds occupancy floor (R2's 128-VGPR cap spilled
// wreg[81] -> 1.9 GB scratch traffic, 2x regression). Row-major tap
// processing keeps live x-values at 6 floats instead of 24.
// Each thread owns one output channel (81 weights in VGPRs). Ring of 3
// accumulators handles kd as d streams; min over d' online; softmax via
// 16-lane shuffles (co = lane&15).

#define CH 8  // d-slices per staged chunk

// apply taps (o,kh) for current (ci, row): 3 kw x 4 p x 3 kd FMAs
#define TAPS(o, kh)                                                        \
    _Pragma("unroll")                                                      \
    for (int kw = 0; kw < 3; ++kw) {                                       \
        const float wk0 = wreg[ci * 27 + 0  + (kh) * 3 + kw];              \
        const float wk1 = wreg[ci * 27 + 9  + (kh) * 3 + kw];              \
        const float wk2 = wreg[ci * 27 + 18 + (kh) * 3 + kw];              \
        _Pragma("unroll")                                                  \
        for (int p = 0; p < 4; ++p) {                                      \
            const float xv = row[kw + p];                                  \
            A2[o][p] = fmaf(xv, wk0, A2[o][p]); /* d' = d   */             \
            A1[o][p] = fmaf(xv, wk1, A1[o][p]); /* d' = d-1 */             \
            A0[o][p] = fmaf(xv, wk2, A0[o][p]); /* d' = d-2 */             \
        }                                                                  \
    }

__global__ __launch_bounds__(256) void conv3d_min_softmax(
    const float* __restrict__ x,     // [16,3,64,64,64]
    const float* __restrict__ wgt,   // [16,3,3,3,3]
    const float* __restrict__ bias,  // [16]
    float* __restrict__ out)         // [16,16,62,62]
{
    const int tid = threadIdx.x;
    const int co  = tid & 15;          // output channel on lane bits 0..3
    const int s   = tid >> 4;          // 0..15 strip id
    const int hh  = (s >> 2) * 2;      // output rows hh, hh+1 (0,2,4,6)
    const int ww  = (s & 3) * 4;       // output cols ww..ww+3 (0,4,8,12)
    const int n   = blockIdx.z;
    const int h0  = blockIdx.y * 8;    // 8 h-tiles cover rows 0..63 (62 valid)
    const int w0  = blockIdx.x * 16;   // 4 w-tiles cover cols 0..63 (62 valid)

    // staged x: 3 ci x CH d x 10 rows x 20 cols (18 valid; stride 20 keeps
    // float4 alignment and conflict-free banking)
    __shared__ __align__(16) float sx[3][CH][10][20];

    // per-thread weights: idx = ci*27 + kd*9 + kh*3 + kw
    float wreg[81];
#pragma unroll
    for (int i = 0; i < 81; ++i) wreg[i] = wgt[co * 81 + i];

    // ring: A0 completes this step (kd=2), A1 next (kd=1), A2 after (kd=0)
    float A0[2][4], A1[2][4], A2[2][4], mv[2][4];
#pragma unroll
    for (int o = 0; o < 2; ++o)
#pragma unroll
        for (int p = 0; p < 4; ++p) {
            A0[o][p] = A1[o][p] = A2[o][p] = 0.f;
            mv[o][p] = 1e30f;
        }

    const float* xn = x + (size_t)n * 3 * 64 * 64 * 64;

    for (int c = 0; c < 64 / CH; ++c) {
        const int d0 = c * CH;
        // ---- stage 3 x CH x 10 x 18(->20) slice: 1200 float4 ----
        __syncthreads();
        for (int F = tid; F < 3 * CH * 10 * 5; F += 256) {
            int rowid = F / 5;               // ci*(CH*10) + dd*10 + r
            int g     = F - rowid * 5;       // col group (4 floats)
            int ci    = rowid / (CH * 10);
            int rem   = rowid - ci * (CH * 10);
            int dd    = rem / 10;
            int r     = rem - dd * 10;
            int gh    = min(h0 + r, 63);     // clamp: edge halo, unused
            int gw    = min(w0 + g * 4, 60); // clamp: cols >=62 unused
            const float4 v = *(const float4*)
                &xn[(((size_t)ci * 64 + d0 + dd) * 64 + gh) * 64 + gw];
            *(float4*)&sx[ci][dd][r][g * 4] = v;
        }
        __syncthreads();

        // ---- compute CH d-steps from LDS ----
#pragma unroll 2
        for (int dd = 0; dd < CH; ++dd) {
#pragma unroll
            for (int ci = 0; ci < 3; ++ci) {
#pragma unroll
                for (int r = 0; r < 4; ++r) {
                    const float4 a = *(const float4*)&sx[ci][dd][hh + r][ww];
                    const float2 b = *(const float2*)&sx[ci][dd][hh + r][ww + 4];
                    const float row[6] = {a.x, a.y, a.z, a.w, b.x, b.y};
                    if (r == 0) { TAPS(0, 0) }
                    if (r == 1) { TAPS(0, 1) TAPS(1, 0) }
                    if (r == 2) { TAPS(0, 2) TAPS(1, 1) }
                    if (r == 3) { TAPS(1, 2) }
                }
            }
            const int d = d0 + dd;
            if (d >= 2) {
#pragma unroll
                for (int o = 0; o < 2; ++o)
#pragma unroll
                    for (int p = 0; p < 4; ++p)
                        mv[o][p] = fminf(mv[o][p], A0[o][p]);
            }
#pragma unroll
            for (int o = 0; o < 2; ++o)
#pragma unroll
                for (int p = 0; p < 4; ++p) {
                    A0[o][p] = A1[o][p];
                    A1[o][p] = A2[o][p];
                    A2[o][p] = 0.f;
                }
        }
    }

    // ---- epilogue: bias, softmax over 16 channels (lanes), store ----
    const float bv = bias[co];
#pragma unroll
    for (int o = 0; o < 2; ++o) {
        const int hp = h0 + hh + o;
#pragma unroll
        for (int p = 0; p < 4; ++p) {
            float v = mv[o][p] + bv;
            float mx = v;
#pragma unroll
            for (int off = 1; off < 16; off <<= 1)
                mx = fmaxf(mx, __shfl_xor(mx, off, 64));
            float e = __expf(v - mx);
            float sum = e;
#pragma unroll
            for (int off = 1; off < 16; off <<= 1)
                sum += __shfl_xor(sum, off, 64);
            const int wp = w0 + ww + p;
            if (hp < 62 && wp < 62)
                out[(((size_t)n * 16 + co) * 62 + hp) * 62 + wp] = e / sum;
        }
    }
}

extern "C" void kernel_launch(void* const* d_in, const int* in_sizes, int n_in,
                              void* d_out, int out_size, void* d_ws, size_t ws_size,
                              hipStream_t stream) {
    const float* x    = (const float*)d_in[0];
    const float* wgt  = (const float*)d_in[1];
    const float* bias = (const float*)d_in[2];
    float* out        = (float*)d_out;
    dim3 grid(4, 8, 16);   // (w-tiles, h-tiles, n)
    dim3 block(256);
    hipLaunchKernelGGL(conv3d_min_softmax, grid, block, 0, stream,
                       x, wgt, bias, out);
}